// Round 14
// baseline (543.154 us; speedup 1.0000x reference)
//
#include <hip/hip_runtime.h>
#include <hip/hip_bf16.h>
#include <math.h>

#define TPB  256     // phaseA / phaseB / refine
#define RTPB 128     // rescue_A: thread per row
#define RW   64      // rescue_B: wave per row
#define RGRID 2048
#define EPS_GAP 1e-4f

typedef unsigned int u32;
typedef unsigned long long u64;
typedef __attribute__((ext_vector_type(8))) short bf16x8;
typedef __attribute__((ext_vector_type(4))) float f32x4;

// ============ analytic fp32 scan: O(8) per level =============================
__device__ __forceinline__ int scan_fast(const float* x, float scale,
                                         float* residual, bool protect, bool& flag){
    float aa[8]; int neg=0; float S=0.f;
    #pragma unroll
    for (int k=0;k<8;k++){
        float v=x[k]; float av=fabsf(v);
        aa[k]=av; S+=av; neg |= (v<0.f)?(1<<k):0;
    }
    float t1=-1e30f,t2=-1e30f,t3=-1e30f; int p1=0,p2=0;
    #pragma unroll
    for (int k=0;k<8;k++){
        float v=aa[k];
        bool g1=v>t1, g2=v>t2, g3=v>t3;
        t3 = g2 ? t2 : (g3 ? v : t3);
        t2 = g1 ? t1 : (g2 ? v : t2);
        p2 = g1 ? p1 : (g2 ? k : p2);
        t1 = g1 ? v : t1;
        p1 = g1 ? k : p1;
    }
    float n1=1e30f,n2v=1e30f; int m1=0;
    #pragma unroll
    for (int k=0;k<8;k++){
        float v=aa[k];
        bool l1=v<n1, l2=v<n2v;
        n2v = l1 ? n1 : (l2 ? v : n2v);
        n1  = l1 ? v : n1;
        m1  = l1 ? k : m1;
    }
    int bi = min(p1,p2), bj = max(p1,p2);
    float pv = 2.f*(t1+t2), pr = 2.f*(t1+t3);
    int par = __builtin_popcount((unsigned)neg)&1;
    float hv, hr; int hb;
    if (par==0){ hv=S;          hb=neg;           hr=S-2.f*(n1+n2v); }
    else       { hv=S-2.f*n1;   hb=neg^(1<<m1);   hr=S-2.f*n2v; }
    bool pair = (pv >= hv);
    float best = pair? pv: hv, alt = pair? hv: pv;
    float second = fmaxf(alt, fmaxf(pr,hr));
    if (protect) flag = flag || ((best-second) < EPS_GAP);
    int s = (((neg>>bi)&1)<<1) | ((neg>>bj)&1);
    int pidx = 4*(7*bi - ((bi*(bi-1))>>1) + (bj-bi-1)) + s;
    int hidx = 112 + (hb>>1);
    float sI = ((neg>>bi)&1)? scale : -scale;
    float sJ = ((neg>>bj)&1)? scale : -scale;
    #pragma unroll
    for (int k=0;k<8;k++){
        float cp = ((k==bi)? sI:0.f) + ((k==bj)? sJ:0.f);
        float ch = ((hb>>k)&1)? 0.5f*scale : -0.5f*scale;
        residual[k] += (pair? cp : ch);
    }
    return pair? pidx : hidx;
}

// ============ analytic f64 scan (rescue) ======================================
__device__ __forceinline__ int scan_fast_f64(const double* x, double scale,
                                             double* residual){
    double aa[8]; int neg=0; double S=0.0;
    #pragma unroll
    for (int k=0;k<8;k++){
        double v=x[k]; double av=fabs(v);
        aa[k]=av; S+=av; neg |= (v<0.0)?(1<<k):0;
    }
    double t1=-1e300,t2=-1e300; int p1=0,p2=0;
    #pragma unroll
    for (int k=0;k<8;k++){
        double v=aa[k];
        bool g1=v>t1, g2=v>t2;
        t2 = g1 ? t1 : (g2 ? v : t2);
        p2 = g1 ? p1 : (g2 ? k : p2);
        t1 = g1 ? v : t1;
        p1 = g1 ? k : p1;
    }
    double n1=1e300; int m1=0;
    #pragma unroll
    for (int k=0;k<8;k++){
        double v=aa[k];
        bool l1=v<n1;
        n1 = l1 ? v : n1;
        m1 = l1 ? k : m1;
    }
    int bi = min(p1,p2), bj = max(p1,p2);
    double pv = 2.0*(t1+t2);
    int par = __builtin_popcount((unsigned)neg)&1;
    double hv; int hb;
    if (par==0){ hv=S;          hb=neg; }
    else       { hv=S-2.0*n1;   hb=neg^(1<<m1); }
    bool pair = (pv >= hv);
    int s = (((neg>>bi)&1)<<1) | ((neg>>bj)&1);
    int pidx = 4*(7*bi - ((bi*(bi-1))>>1) + (bj-bi-1)) + s;
    int hidx = 112 + (hb>>1);
    double sI = ((neg>>bi)&1)? scale : -scale;
    double sJ = ((neg>>bj)&1)? scale : -scale;
    #pragma unroll
    for (int k=0;k<8;k++){
        double cp = ((k==bi)? sI:0.0) + ((k==bj)? sJ:0.0);
        double ch = ((hb>>k)&1)? 0.5*scale : -0.5*scale;
        residual[k] += (pair? cp : ch);
    }
    return pair? pidx : hidx;
}

// ============ helpers for MFMA phase B =======================================
__device__ __forceinline__ unsigned short f2bf(float x){
    union{float f; u32 u;} c; c.f = x;
    u32 u = c.u + 0x7fffu + ((c.u>>16)&1u);
    return (unsigned short)(u>>16);
}
__device__ __forceinline__ u32 pk2(float a, float b){
    union { __hip_bfloat162 h; u32 u; } cv;
    cv.h = __float22bfloat162_rn(make_float2(a,b));
    return cv.u;
}

#define BT_PITCH 264
#define E_PITCH  260
#define SCR_PITCH 68

#define EP4(i,jn,J,W) { \
    float P=(qf[i]+qf[jn])*IS2, M=(qf[i]-qf[jn])*IS2; \
    float e0=__expf(fmaf(-LG2,bcxL[(J)+0],P)); \
    float e1=__expf(fmaf(-LG2,bcxL[(J)+1],M)); \
    float e2=__expf(fmaf(-LG2,bcxL[(J)+2],-M)); \
    float e3=__expf(fmaf(-LG2,bcxL[(J)+3],-P)); \
    den += ((e0+e1)+(e2+e3)); \
    ESH[((W)+0)*E_PITCH + tid]=pk2(e0,e1); \
    ESH[((W)+1)*E_PITCH + tid]=pk2(e2,e3); }

#define LOV(Lx) (s01[(Lx)&3]+s23[(Lx)>>2])
#define EH8(h,J,W,L0,L1,L2,L3,L4,L5,L6,L7) { \
    float hv=s45[(h)&3]+s67[(h)>>2]; \
    float e0=__expf(fmaf(-LG2,bcxL[(J)+0],(LOV(L0)+hv)*HS2)); \
    float e1=__expf(fmaf(-LG2,bcxL[(J)+1],(LOV(L1)+hv)*HS2)); \
    float e2=__expf(fmaf(-LG2,bcxL[(J)+2],(LOV(L2)+hv)*HS2)); \
    float e3=__expf(fmaf(-LG2,bcxL[(J)+3],(LOV(L3)+hv)*HS2)); \
    float e4=__expf(fmaf(-LG2,bcxL[(J)+4],(LOV(L4)+hv)*HS2)); \
    float e5=__expf(fmaf(-LG2,bcxL[(J)+5],(LOV(L5)+hv)*HS2)); \
    float e6=__expf(fmaf(-LG2,bcxL[(J)+6],(LOV(L6)+hv)*HS2)); \
    float e7=__expf(fmaf(-LG2,bcxL[(J)+7],(LOV(L7)+hv)*HS2)); \
    den += (((e0+e1)+(e2+e3))+((e4+e5)+(e6+e7))); \
    ESH[((W)+0)*E_PITCH + tid]=pk2(e0,e1); \
    ESH[((W)+1)*E_PITCH + tid]=pk2(e2,e3); \
    ESH[((W)+2)*E_PITCH + tid]=pk2(e4,e5); \
    ESH[((W)+3)*E_PITCH + tid]=pk2(e6,e7); }

#define EFLUSH(c) { \
    union { u32 u[4]; bf16x8 v; } Af; \
    const unsigned short* bp = BtT + pp*BT_PITCH + qq*8 + (c)*32; \
    bf16x8 b0 = *(const bf16x8*)(const void*)(bp); \
    bf16x8 b1 = *(const bf16x8*)(const void*)(bp + 16*BT_PITCH); \
    bf16x8 b2 = *(const bf16x8*)(const void*)(bp + 32*BT_PITCH); \
    bf16x8 b3 = *(const bf16x8*)(const void*)(bp + 48*BT_PITCH); \
    _Pragma("unroll") for (int s4=0;s4<4;s4++){ \
        const u32* ep = ESH + (4*qq)*E_PITCH + wbase + 16*s4 + pp; \
        Af.u[0]=ep[0]; Af.u[1]=ep[E_PITCH]; Af.u[2]=ep[2*E_PITCH]; Af.u[3]=ep[3*E_PITCH]; \
        acc[s4][0]=__builtin_amdgcn_mfma_f32_16x16x32_bf16(Af.v,b0,acc[s4][0],0,0,0); \
        acc[s4][1]=__builtin_amdgcn_mfma_f32_16x16x32_bf16(Af.v,b1,acc[s4][1],0,0,0); \
        acc[s4][2]=__builtin_amdgcn_mfma_f32_16x16x32_bf16(Af.v,b2,acc[s4][2],0,0,0); \
        acc[s4][3]=__builtin_amdgcn_mfma_f32_16x16x32_bf16(Af.v,b3,acc[s4][3],0,0,0); \
    } }

// ============ K_A: fp32 MLP + analytic scan; writes q + packed idxs into out ==
__global__ __launch_bounds__(TPB) void e8_phaseA(
    const float* __restrict__ g_obs,
    const float* __restrict__ pw1, const float* __restrict__ pb1,
    const float* __restrict__ pw2, const float* __restrict__ pb2,
    const float* __restrict__ glogdecay,
    u32* __restrict__ cnt, u32* __restrict__ list,
    unsigned char* __restrict__ flags, int useCompact,
    float* __restrict__ out, int B)
{
    __shared__ float obsF[TPB*17];     // 17.4 KB coalesced obs staging
    const int tid = threadIdx.x;
    const int row = blockIdx.x*TPB + tid;
    const bool active = row < B;
    const int lane = tid & 63;

    {
        const size_t base = (size_t)blockIdx.x*TPB*14;
        const size_t lim  = (size_t)B*14;
        for (int t = tid; t < TPB*14; t += TPB){
            size_t g = base + (size_t)t;
            float v = (g < lim) ? g_obs[g] : 0.f;
            int r = t/14, c = t - r*14;
            obsF[r*17 + c] = v;
        }
    }
    __syncthreads();

    float qf[8];
    int idxs[8] = {0,0,0,0,0,0,0,0};
    bool flag = false;
    {
        float ob[14];
        #pragma unroll
        for (int j=0;j<14;j++) ob[j]=obsF[tid*17+j];
        float qa[8];
        #pragma unroll
        for (int m=0;m<8;m++) qa[m]=pb2[m];
        #pragma unroll 1
        for (int k=0;k<32;k++){
            float a = pb1[k];
            #pragma unroll
            for (int j=0;j<14;j++) a = fmaf(pw1[k*14+j], ob[j], a);
            float h = 0.5f*a*(1.f+erff(a*0.70710678f));
            #pragma unroll
            for (int m=0;m<8;m++) qa[m] = fmaf(pw2[m*32+k], h, qa[m]);
        }
        float n2=0.f;
        #pragma unroll
        for (int m=0;m<8;m++) n2 = fmaf(qa[m],qa[m],n2);
        float nr = fmaxf(sqrtf(n2), 1e-12f);
        float sc = 1.41421356237309505f/nr;
        float residual[8];
        #pragma unroll
        for (int m=0;m<8;m++){ qf[m]=qa[m]*sc; residual[m]=qf[m]; }

        float decay = expf(glogdecay[0]);
        float dpow = 1.f;
        #pragma unroll
        for (int lvl=0; lvl<8; ++lvl){
            float rs = 0.5f*dpow;
            float x[8];
            #pragma unroll
            for (int k=0;k<8;k++) x[k]=residual[k]*rs;
            idxs[lvl] = scan_fast(x, 2.f/dpow, residual, (lvl<3), flag);
            dpow *= decay;
        }
    }
    flag = flag && active;

    if (useCompact){
        u64 mask = __ballot(flag);
        if (mask){
            int leader = __builtin_ctzll(mask);
            u32 base = 0;
            if (lane == leader) base = atomicAdd(cnt, (u32)__builtin_popcountll(mask));
            base = __shfl(base, leader, 64);
            if (flag){
                u32 pos = (u32)__builtin_popcountll(mask & ((1ull<<lane)-1ull));
                list[base+pos] = (u32)row;
            }
        }
    } else if (active){
        flags[row] = flag ? 1 : 0;
    }

    if (active){
        float* orow = out + (size_t)row*56;
        *(float4*)(orow+0) = make_float4(qf[0],qf[1],qf[2],qf[3]);
        *(float4*)(orow+4) = make_float4(qf[4],qf[5],qf[6],qf[7]);
        u32 iw0 = (u32)idxs[1] | ((u32)idxs[2]<<8) | ((u32)idxs[3]<<16) | ((u32)idxs[4]<<24);
        u32 iw1 = (u32)idxs[5] | ((u32)idxs[6]<<8) | ((u32)idxs[7]<<16);
        union{ u32 u[2]; float2 f; } iv; iv.u[0]=iw0; iv.u[1]=iw1;
        *(float2*)(orow+8) = iv.f;
    }
}

// ============ K_B: MFMA softmax-GEMM + hard gathers (R9 config, converged) ====
__global__ __launch_bounds__(TPB) void e8_phaseB(
    const float* __restrict__ lemb, const float* __restrict__ bcp,
    const float* __restrict__ rcpar, const float* __restrict__ bcx,
    const float* __restrict__ glogdecay,
    float* __restrict__ out, int B)
{
    const float IS2 = 0.70710678118654752f;
    const float HS2 = 0.35355339059327376f;
    const float LG2 = 0.69314718055994531f;

    __shared__ __align__(16) unsigned short BtT[64*BT_PITCH]; // 33792 B bf16 L^T
    __shared__ __align__(16) char UN[17408];                  // E / scratch union
    __shared__ float bcxL[240];
    u32*   ESH  = (u32*)UN;
    float* scrF = (float*)UN;

    const int tid  = threadIdx.x;
    const int row  = blockIdx.x*TPB + tid;
    const bool active = row < B;
    const int lane = tid & 63;
    const int qq = lane >> 4, pp = lane & 15;
    const int wbase = tid & 192;       // wave index * 64

    for (int t = tid; t < 2048; t += TPB)
        BtT[(56 + (t>>8))*BT_PITCH + (t&255)] = 0;
    for (int t = tid; t < 1024; t += TPB)
        BtT[(t>>4)*BT_PITCH + 240 + (t&15)] = 0;
    for (int t = tid; t < 12480; t += TPB){
        int k = t/52, c = t - k*52;
        BtT[c*BT_PITCH + k] = f2bf(lemb[t]);
    }
    for (int t = tid; t < 960; t += TPB){
        int k = t>>2, c = 52 + (t&3);
        BtT[c*BT_PITCH + k] = f2bf(bcp[t]);
    }
    for (int t = tid; t < 240; t += TPB) bcxL[t] = bcx[t];

    float qf[8];
    u32 iw0=0, iw1=0;
    if (active){
        const float* orow = out + (size_t)row*56;
        float4 q0 = *(const float4*)(orow+0);
        float4 q1 = *(const float4*)(orow+4);
        qf[0]=q0.x; qf[1]=q0.y; qf[2]=q0.z; qf[3]=q0.w;
        qf[4]=q1.x; qf[5]=q1.y; qf[6]=q1.z; qf[7]=q1.w;
        union{ float2 f; u32 u[2]; } iv;
        iv.f = *(const float2*)(orow+8);
        iw0 = iv.u[0]; iw1 = iv.u[1];
    } else {
        #pragma unroll
        for (int m=0;m<8;m++) qf[m]=0.f;
    }
    float decay = expf(glogdecay[0]);
    __syncthreads();

    float s01[4], s23[4], s45[4], s67[4];
    {
        float a01p=qf[0]+qf[1], a01m=qf[0]-qf[1];
        float a23p=qf[2]+qf[3], a23m=qf[2]-qf[3];
        float a45p=qf[4]+qf[5], a45m=qf[4]-qf[5];
        float a67p=qf[6]+qf[7], a67m=qf[6]-qf[7];
        s01[0]=a01p; s01[1]=-a01m; s01[2]=a01m; s01[3]=-a01p;
        s23[0]=a23p; s23[1]=-a23m; s23[2]=a23m; s23[3]=-a23p;
        s45[0]=a45p; s45[1]=-a45m; s45[2]=a45m; s45[3]=-a45p;
        s67[0]=a67p; s67[1]=-a67m; s67[2]=a67m; s67[3]=-a67p;
    }

    f32x4 acc[4][4];
    #pragma unroll
    for (int s=0;s<4;s++)
        #pragma unroll
        for (int n=0;n<4;n++)
            acc[s][n] = f32x4{0.f,0.f,0.f,0.f};
    float den = 0.f;

    EP4(0,1,  0, 0) EP4(0,2,  4, 2) EP4(0,3,  8, 4) EP4(0,4, 12, 6)
    EP4(0,5, 16, 8) EP4(0,6, 20,10) EP4(0,7, 24,12) EP4(1,2, 28,14)
    EFLUSH(0)
    EP4(1,3, 32, 0) EP4(1,4, 36, 2) EP4(1,5, 40, 4) EP4(1,6, 44, 6)
    EP4(1,7, 48, 8) EP4(2,3, 52,10) EP4(2,4, 56,12) EP4(2,5, 60,14)
    EFLUSH(1)
    EP4(2,6, 64, 0) EP4(2,7, 68, 2) EP4(3,4, 72, 4) EP4(3,5, 76, 6)
    EP4(3,6, 80, 8) EP4(3,7, 84,10) EP4(4,5, 88,12) EP4(4,6, 92,14)
    EFLUSH(2)
    EP4(4,7, 96, 0) EP4(5,6,100, 2) EP4(5,7,104, 4) EP4(6,7,108, 6)
    EH8(0,112, 8, 0,3,5,6,9,10,12,15)
    EH8(1,120,12, 1,2,4,7,8,11,13,14)
    EFLUSH(3)
    EH8(2,128, 0, 1,2,4,7,8,11,13,14)
    EH8(3,136, 4, 0,3,5,6,9,10,12,15)
    EH8(4,144, 8, 1,2,4,7,8,11,13,14)
    EH8(5,152,12, 0,3,5,6,9,10,12,15)
    EFLUSH(4)
    EH8(6,160, 0, 0,3,5,6,9,10,12,15)
    EH8(7,168, 4, 1,2,4,7,8,11,13,14)
    EH8(8,176, 8, 1,2,4,7,8,11,13,14)
    EH8(9,184,12, 0,3,5,6,9,10,12,15)
    EFLUSH(5)
    EH8(10,192, 0, 0,3,5,6,9,10,12,15)
    EH8(11,200, 4, 1,2,4,7,8,11,13,14)
    EH8(12,208, 8, 0,3,5,6,9,10,12,15)
    EH8(13,216,12, 1,2,4,7,8,11,13,14)
    EFLUSH(6)
    EH8(14,224, 0, 1,2,4,7,8,11,13,14)
    EH8(15,232, 4, 0,3,5,6,9,10,12,15)
    #pragma unroll
    for (int w2=8; w2<16; w2++) ESH[w2*E_PITCH + tid]=0u;
    EFLUSH(7)

    __syncthreads();

    float emb[56];
    float* scr = scrF + (tid>>6)*(16*SCR_PITCH);
    #pragma unroll
    for (int s=0;s<4;s++){
        #pragma unroll
        for (int n=0;n<4;n++){
            #pragma unroll
            for (int r=0;r<4;r++)
                scr[(4*qq+r)*SCR_PITCH + 16*n + pp] = acc[s][n][r];
        }
        if ((lane>>4) == s){
            const float4* rp = (const float4*)(scr + pp*SCR_PITCH);
            #pragma unroll
            for (int t=0;t<14;t++){
                float4 v = rp[t];
                emb[4*t]=v.x; emb[4*t+1]=v.y; emb[4*t+2]=v.z; emb[4*t+3]=v.w;
            }
        }
    }

    if (active){
        float rden = 1.f/den;
        #pragma unroll
        for (int k=0;k<56;k++) emb[k] *= rden;

        int i1 = iw0 & 255, i2 = (iw0>>8)&255, i3 = (iw0>>16)&255, i4 = (iw0>>24)&255;
        int i5 = iw1 & 255, i6 = (iw1>>8)&255, i7 = (iw1>>16)&255;

        float dp = decay;
        #define DO_G2(LVL, IV) { \
            float ild = 1.0f/dp; \
            const float4* ep4 = (const float4*)(lemb + ((size_t)(LVL)*240 + (size_t)(IV))*52); \
            _Pragma("unroll") for (int t4=0;t4<13;t4++){ float4 v=ep4[t4]; \
                emb[4*t4+0]=fmaf(ild,v.x,emb[4*t4+0]); emb[4*t4+1]=fmaf(ild,v.y,emb[4*t4+1]); \
                emb[4*t4+2]=fmaf(ild,v.z,emb[4*t4+2]); emb[4*t4+3]=fmaf(ild,v.w,emb[4*t4+3]); } \
            float4 cv = *(const float4*)(rcpar + ((size_t)((LVL)-1)*240 + (size_t)(IV))*4); \
            emb[52]=fmaf(ild,cv.x,emb[52]); emb[53]=fmaf(ild,cv.y,emb[53]); \
            emb[54]=fmaf(ild,cv.z,emb[54]); emb[55]=fmaf(ild,cv.w,emb[55]); \
            dp *= decay; }
        DO_G2(1,i1) DO_G2(2,i2) DO_G2(3,i3) DO_G2(4,i4)
        DO_G2(5,i5) DO_G2(6,i6) DO_G2(7,i7)
        #undef DO_G2

        float4* o4 = (float4*)(out + (size_t)row*56);
        #pragma unroll
        for (int t=0;t<14;t++)
            o4[t] = make_float4(emb[4*t], emb[4*t+1], emb[4*t+2], emb[4*t+3]);
    }
}

// ============ K2a: rescue part A — f64 MLP+scan, thread per row ===============
__global__ __launch_bounds__(RTPB) void e8_rescueA(
    const float* __restrict__ g_obs,
    const float* __restrict__ pw1, const float* __restrict__ pb1,
    const float* __restrict__ pw2, const float* __restrict__ pb2,
    const float* __restrict__ glogdecay,
    const u32* __restrict__ cnt, const u32* __restrict__ list,
    const unsigned char* __restrict__ flags, int useCompact,
    float* __restrict__ out, int B)
{
    const int tid = threadIdx.x;
    int row = -1;
    if (useCompact){
        u32 c = *cnt;
        if ((u32)(blockIdx.x*RTPB) >= c) return;
        u32 gid = blockIdx.x*RTPB + tid;
        if (gid >= c) return;
        row = (int)list[gid];
    } else {
        row = blockIdx.x*RTPB + tid;
        if (row >= B || !flags[row]) return;
    }

    double ob[14];
    #pragma unroll
    for (int j=0;j<14;j++) ob[j] = (double)g_obs[(size_t)row*14+j];
    double qa[8];
    #pragma unroll
    for (int m=0;m<8;m++) qa[m] = (double)pb2[m];
    #pragma unroll 1
    for (int k=0;k<32;k++){
        double a = (double)pb1[k];
        #pragma unroll
        for (int j=0;j<14;j++) a += (double)pw1[k*14+j]*ob[j];
        double hk = 0.5*a*(1.0 + erf(a*0.70710678118654752440));
        #pragma unroll
        for (int m=0;m<8;m++) qa[m] += (double)pw2[m*32+k]*hk;
    }
    double n2 = 0.0;
    #pragma unroll
    for (int m=0;m<8;m++) n2 += qa[m]*qa[m];
    double nr = sqrt(n2); if (nr < 1e-12) nr = 1e-12;
    double q[8], residual[8];
    #pragma unroll
    for (int m=0;m<8;m++){ q[m] = qa[m]/nr*1.4142135623730951; residual[m]=q[m]; }

    double decay_d = exp((double)glogdecay[0]);
    double dpow = 1.0;
    int idxs[8] = {0,0,0,0,0,0,0,0};
    #pragma unroll
    for (int lvl=0; lvl<8; ++lvl){
        double rs = 0.5*dpow;
        double x[8];
        #pragma unroll
        for (int k=0;k<8;k++) x[k]=residual[k]*rs;
        idxs[lvl] = scan_fast_f64(x, 2.0/dpow, residual);
        dpow *= decay_d;
    }

    float* orow = out + (size_t)row*56;
    *(float4*)(orow+0) = make_float4((float)q[0],(float)q[1],(float)q[2],(float)q[3]);
    *(float4*)(orow+4) = make_float4((float)q[4],(float)q[5],(float)q[6],(float)q[7]);
    u32 iw0 = (u32)idxs[1] | ((u32)idxs[2]<<8) | ((u32)idxs[3]<<16) | ((u32)idxs[4]<<24);
    u32 iw1 = (u32)idxs[5] | ((u32)idxs[6]<<8) | ((u32)idxs[7]<<16);
    union{ u32 u[2]; float2 f; } iv; iv.u[0]=iw0; iv.u[1]=iw1;
    *(float2*)(orow+8) = iv.f;
}

// ============ K2b: rescue part B — fp32 column-parallel phaseB, wave per row ==
// R13 post-mortem: fp32 kernel ALONE hit 256 VGPR + ~500 dwords/lane spill —
// the scheduler hoists the 240 fully-unrolled independent global loads
// arbitrarily far ahead (unbounded software pipelining). Fix: pin schedule
// regions with sched_barrier(0) after every e-group (<=8 loads in flight per
// region). Same instructions, same order => bit-identical output.
#define SBAR __builtin_amdgcn_sched_barrier(0);
#define RHm(h,m) { \
    float sims = (lo16v[((m)<<1)|((__builtin_popcount(m)&1)^(__builtin_popcount(h)&1))] + hi16v[h])*HS2; \
    float e = __expf(sims - bcxS[112+((h)<<3)+(m)]*LG2); \
    den += e; \
    emb_c = fmaf(e, colp[(size_t)(112+((h)<<3)+(m))*cstr], emb_c); }
#define RH8(h) RHm(h,0) RHm(h,1) RHm(h,2) RHm(h,3) RHm(h,4) RHm(h,5) RHm(h,6) RHm(h,7) SBAR
#define RP1(j) { \
    float e = __expf(sv - bcxS[j]*LG2); den += e; \
    emb_c = fmaf(e, colp[(size_t)(j)*cstr], emb_c); }
#define RP(pc,i,j2) { \
    float a=qf[i], b=qf[j2]; float p=a+b, mm=a-b; float sv; \
    sv =  p*IS2; RP1(4*(pc)+0) \
    sv = mm*IS2; RP1(4*(pc)+1) \
    sv = -mm*IS2; RP1(4*(pc)+2) \
    sv = -p*IS2; RP1(4*(pc)+3) } SBAR

__global__ __launch_bounds__(RW) void e8_rescueB(
    const float* __restrict__ lemb, const float* __restrict__ bcp,
    const float* __restrict__ rcpar, const float* __restrict__ bcx,
    const float* __restrict__ glogdecay,
    const u32* __restrict__ cnt, const u32* __restrict__ list,
    const unsigned char* __restrict__ flags, int useCompact,
    float* __restrict__ out, int B)
{
    const float IS2 = 0.70710678118654752f;
    const float HS2 = 0.35355339059327376f;
    const float LG2 = 0.69314718055994531f;
    __shared__ float bcxS[240];
    const int c = threadIdx.x;         // lane == tid (single wave)

    u32 nwork = 0;
    if (useCompact){
        nwork = *cnt;
        if (blockIdx.x >= nwork) return;           // wave-uniform early-out
    }
    for (int t = c; t < 240; t += RW) bcxS[t] = bcx[t];
    // single wave: in-order LDS, no barrier needed

    const float* colp; size_t cstr;
    if (c < 52)      { colp = lemb + c;        cstr = 52; }
    else if (c < 56) { colp = bcp + (c - 52);  cstr = 4;  }
    else             { colp = lemb;            cstr = 0;  }

    float decayf = (float)exp((double)glogdecay[0]);

    for (u32 wi = blockIdx.x; ; wi += gridDim.x){
        int row;
        if (useCompact){
            if (wi >= nwork) break;
            row = (int)list[wi];
        } else {
            if (wi >= (u32)B) break;
            if (!flags[wi]) continue;
            row = (int)wi;
        }

        // ---- read qf + idxs written by rescue_A (uniform broadcast loads) ----
        const float* orow = out + (size_t)row*56;
        float4 q0 = *(const float4*)(orow+0);
        float4 q1 = *(const float4*)(orow+4);
        float qf[8] = {q0.x,q0.y,q0.z,q0.w,q1.x,q1.y,q1.z,q1.w};
        union{ float2 f; u32 u[2]; } iv;
        iv.f = *(const float2*)(orow+8);
        u32 iw0 = iv.u[0], iw1 = iv.u[1];

        float lo16v[16], hi16v[16];
        {
            float a01p=qf[0]+qf[1], a01m=qf[0]-qf[1];
            float a23p=qf[2]+qf[3], a23m=qf[2]-qf[3];
            float a45p=qf[4]+qf[5], a45m=qf[4]-qf[5];
            float a67p=qf[6]+qf[7], a67m=qf[6]-qf[7];
            float s01[4]={a01p,-a01m,a01m,-a01p};
            float s23[4]={a23p,-a23m,a23m,-a23p};
            float s45[4]={a45p,-a45m,a45m,-a45p};
            float s67[4]={a67p,-a67m,a67m,-a67p};
            #pragma unroll
            for (int p=0;p<16;p++){ lo16v[p]=s01[p&3]+s23[(p>>2)&3]; hi16v[p]=s45[p&3]+s67[(p>>2)&3]; }
        }

        float emb_c = 0.f, den = 0.f;
        RH8(0)  RH8(1)  RH8(2)  RH8(3)  RH8(4)  RH8(5)  RH8(6)  RH8(7)
        RH8(8)  RH8(9)  RH8(10) RH8(11) RH8(12) RH8(13) RH8(14) RH8(15)
        RP(0,0,1)  RP(1,0,2)  RP(2,0,3)  RP(3,0,4)  RP(4,0,5)  RP(5,0,6)  RP(6,0,7)
        RP(7,1,2)  RP(8,1,3)  RP(9,1,4)  RP(10,1,5) RP(11,1,6) RP(12,1,7)
        RP(13,2,3) RP(14,2,4) RP(15,2,5) RP(16,2,6) RP(17,2,7)
        RP(18,3,4) RP(19,3,5) RP(20,3,6) RP(21,3,7)
        RP(22,4,5) RP(23,4,6) RP(24,4,7)
        RP(25,5,6) RP(26,5,7)
        RP(27,6,7)
        emb_c *= 1.f/den;

        int idxs[8];
        idxs[1]=iw0&255; idxs[2]=(iw0>>8)&255; idxs[3]=(iw0>>16)&255; idxs[4]=(iw0>>24)&255;
        idxs[5]=iw1&255; idxs[6]=(iw1>>8)&255; idxs[7]=(iw1>>16)&255;

        float dp = decayf;
        #pragma unroll
        for (int lvl=1; lvl<8; ++lvl){
            float ild = 1.0f/dp;
            int idx = idxs[lvl];
            float gv;
            if (c < 52)      gv = lemb[((size_t)lvl*240 + (size_t)idx)*52 + c];
            else if (c < 56) gv = rcpar[((size_t)(lvl-1)*240 + (size_t)idx)*4 + (c-52)];
            else             gv = 0.f;
            emb_c = fmaf(ild, gv, emb_c);
            dp *= decayf;
        }

        if (c < 56) out[(size_t)row*56 + c] = emb_c;
    }
}

// ============ K3: gated refinement MLP (standalone, proven R6 version) =======
__global__ __launch_bounds__(TPB) void e8_refine(
    const float* __restrict__ rw1, const float* __restrict__ rb1,
    const float* __restrict__ rw2, const float* __restrict__ rb2,
    const float* __restrict__ rgate,
    float* __restrict__ out, int B)
{
    __shared__ float W1[2704];
    __shared__ float W2T[2704];
    __shared__ float Bv[104];
    const int tid = threadIdx.x;
    for (int t = tid; t < 2704; t += TPB) W1[t] = rw1[t];
    for (int t = tid; t < 2704; t += TPB){
        int m = t/52, k = t - m*52;
        W2T[k*52 + m] = rw2[t];
    }
    for (int t = tid; t < 104; t += TPB) Bv[t] = (t < 52) ? rb1[t] : rb2[t-52];
    __syncthreads();

    const int row = blockIdx.x*TPB + tid;
    if (row >= B) return;
    float* orow = out + (size_t)row*56;
    float emb[52];
    {
        const float4* o4 = (const float4*)orow;
        #pragma unroll
        for (int t=0;t<13;t++){
            float4 v = o4[t];
            emb[4*t]=v.x; emb[4*t+1]=v.y; emb[4*t+2]=v.z; emb[4*t+3]=v.w;
        }
    }
    float sg = 1.f/(1.f+__expf(-rgate[0]));
    float acc[52];
    #pragma unroll
    for (int m=0;m<52;m++) acc[m]=0.f;
    #pragma unroll 1
    for (int k=0;k<52;k++){
        const float4* w1 = (const float4*)(W1 + k*52);
        float a0=0.f,a1=0.f,a2=0.f,a3=0.f;
        #pragma unroll
        for (int t=0;t<13;t++){
            float4 w = w1[t];
            a0=fmaf(w.x,emb[4*t+0],a0); a1=fmaf(w.y,emb[4*t+1],a1);
            a2=fmaf(w.z,emb[4*t+2],a2); a3=fmaf(w.w,emb[4*t+3],a3);
        }
        float a = ((a0+a1)+(a2+a3)) + Bv[k];
        float gk = sg*0.5f*a*(1.f+erff(a*0.70710678f));
        const float4* w2 = (const float4*)(W2T + k*52);
        #pragma unroll
        for (int t=0;t<13;t++){
            float4 w = w2[t];
            acc[4*t+0]=fmaf(gk,w.x,acc[4*t+0]); acc[4*t+1]=fmaf(gk,w.y,acc[4*t+1]);
            acc[4*t+2]=fmaf(gk,w.z,acc[4*t+2]); acc[4*t+3]=fmaf(gk,w.w,acc[4*t+3]);
        }
    }
    float4* o4 = (float4*)orow;
    #pragma unroll
    for (int t=0;t<13;t++){
        float4 v;
        v.x = emb[4*t+0] + fmaf(sg, Bv[52+4*t+0], acc[4*t+0]);
        v.y = emb[4*t+1] + fmaf(sg, Bv[52+4*t+1], acc[4*t+1]);
        v.z = emb[4*t+2] + fmaf(sg, Bv[52+4*t+2], acc[4*t+2]);
        v.w = emb[4*t+3] + fmaf(sg, Bv[52+4*t+3], acc[4*t+3]);
        o4[t] = v;
    }
}

extern "C" void kernel_launch(void* const* d_in, const int* in_sizes, int n_in,
                              void* d_out, int out_size, void* d_ws, size_t ws_size,
                              hipStream_t stream)
{
    const float* obs  = (const float*)d_in[0];
    const float* pw1  = (const float*)d_in[1];
    const float* pb1  = (const float*)d_in[2];
    const float* pw2  = (const float*)d_in[3];
    const float* pb2  = (const float*)d_in[4];
    const float* lemb = (const float*)d_in[5];
    const float* bcp  = (const float*)d_in[6];
    const float* rcp  = (const float*)d_in[7];
    const float* bcx  = (const float*)d_in[8];
    const float* ld   = (const float*)d_in[9];
    const float* rw1  = (const float*)d_in[10];
    const float* rb1  = (const float*)d_in[11];
    const float* rw2  = (const float*)d_in[12];
    const float* rb2  = (const float*)d_in[13];
    const float* rg   = (const float*)d_in[14];

    int B = in_sizes[0] / 14;
    int grid  = (B + TPB - 1) / TPB;
    int rgridA = (B + RTPB - 1) / RTPB;

    bool compact = ws_size >= (size_t)256 + (size_t)B*4;
    u32* cnt  = (u32*)d_ws;
    u32* list = (u32*)d_ws + 64;
    unsigned char* flags = (unsigned char*)d_ws + 256;

    hipMemsetAsync(d_ws, 0, 8, stream);

    e8_phaseA<<<grid, TPB, 0, stream>>>(obs, pw1, pb1, pw2, pb2, ld,
                                        cnt, list, flags, compact?1:0, (float*)d_out, B);
    e8_phaseB<<<grid, TPB, 0, stream>>>(lemb, bcp, rcp, bcx, ld, (float*)d_out, B);
    e8_rescueA<<<rgridA, RTPB, 0, stream>>>(obs, pw1, pb1, pw2, pb2, ld,
                                            cnt, list, flags, compact?1:0, (float*)d_out, B);
    e8_rescueB<<<RGRID, RW, 0, stream>>>(lemb, bcp, rcp, bcx, ld,
                                         cnt, list, flags, compact?1:0, (float*)d_out, B);
    e8_refine<<<grid, TPB, 0, stream>>>(rw1, rb1, rw2, rb2, rg, (float*)d_out, B);
}

// Round 15
// 344.259 us; speedup vs baseline: 1.5777x; 1.5777x over previous
//
#include <hip/hip_runtime.h>
#include <hip/hip_bf16.h>
#include <math.h>

#define TPB  256     // phaseA / phaseB / refine
#define RTPB 128     // rescue_A: thread per row
#define EPS_GAP 1e-4f

typedef unsigned int u32;
typedef unsigned long long u64;
typedef __attribute__((ext_vector_type(8))) short bf16x8;
typedef __attribute__((ext_vector_type(4))) float f32x4;

// ============ analytic fp32 scan: O(8) per level =============================
__device__ __forceinline__ int scan_fast(const float* x, float scale,
                                         float* residual, bool protect, bool& flag){
    float aa[8]; int neg=0; float S=0.f;
    #pragma unroll
    for (int k=0;k<8;k++){
        float v=x[k]; float av=fabsf(v);
        aa[k]=av; S+=av; neg |= (v<0.f)?(1<<k):0;
    }
    float t1=-1e30f,t2=-1e30f,t3=-1e30f; int p1=0,p2=0;
    #pragma unroll
    for (int k=0;k<8;k++){
        float v=aa[k];
        bool g1=v>t1, g2=v>t2, g3=v>t3;
        t3 = g2 ? t2 : (g3 ? v : t3);
        t2 = g1 ? t1 : (g2 ? v : t2);
        p2 = g1 ? p1 : (g2 ? k : p2);
        t1 = g1 ? v : t1;
        p1 = g1 ? k : p1;
    }
    float n1=1e30f,n2v=1e30f; int m1=0;
    #pragma unroll
    for (int k=0;k<8;k++){
        float v=aa[k];
        bool l1=v<n1, l2=v<n2v;
        n2v = l1 ? n1 : (l2 ? v : n2v);
        n1  = l1 ? v : n1;
        m1  = l1 ? k : m1;
    }
    int bi = min(p1,p2), bj = max(p1,p2);
    float pv = 2.f*(t1+t2), pr = 2.f*(t1+t3);
    int par = __builtin_popcount((unsigned)neg)&1;
    float hv, hr; int hb;
    if (par==0){ hv=S;          hb=neg;           hr=S-2.f*(n1+n2v); }
    else       { hv=S-2.f*n1;   hb=neg^(1<<m1);   hr=S-2.f*n2v; }
    bool pair = (pv >= hv);
    float best = pair? pv: hv, alt = pair? hv: pv;
    float second = fmaxf(alt, fmaxf(pr,hr));
    if (protect) flag = flag || ((best-second) < EPS_GAP);
    int s = (((neg>>bi)&1)<<1) | ((neg>>bj)&1);
    int pidx = 4*(7*bi - ((bi*(bi-1))>>1) + (bj-bi-1)) + s;
    int hidx = 112 + (hb>>1);
    float sI = ((neg>>bi)&1)? scale : -scale;
    float sJ = ((neg>>bj)&1)? scale : -scale;
    #pragma unroll
    for (int k=0;k<8;k++){
        float cp = ((k==bi)? sI:0.f) + ((k==bj)? sJ:0.f);
        float ch = ((hb>>k)&1)? 0.5f*scale : -0.5f*scale;
        residual[k] += (pair? cp : ch);
    }
    return pair? pidx : hidx;
}

// ============ analytic f64 scan (rescue) ======================================
__device__ __forceinline__ int scan_fast_f64(const double* x, double scale,
                                             double* residual){
    double aa[8]; int neg=0; double S=0.0;
    #pragma unroll
    for (int k=0;k<8;k++){
        double v=x[k]; double av=fabs(v);
        aa[k]=av; S+=av; neg |= (v<0.0)?(1<<k):0;
    }
    double t1=-1e300,t2=-1e300; int p1=0,p2=0;
    #pragma unroll
    for (int k=0;k<8;k++){
        double v=aa[k];
        bool g1=v>t1, g2=v>t2;
        t2 = g1 ? t1 : (g2 ? v : t2);
        p2 = g1 ? p1 : (g2 ? k : p2);
        t1 = g1 ? v : t1;
        p1 = g1 ? k : p1;
    }
    double n1=1e300; int m1=0;
    #pragma unroll
    for (int k=0;k<8;k++){
        double v=aa[k];
        bool l1=v<n1;
        n1 = l1 ? v : n1;
        m1 = l1 ? k : m1;
    }
    int bi = min(p1,p2), bj = max(p1,p2);
    double pv = 2.0*(t1+t2);
    int par = __builtin_popcount((unsigned)neg)&1;
    double hv; int hb;
    if (par==0){ hv=S;          hb=neg; }
    else       { hv=S-2.0*n1;   hb=neg^(1<<m1); }
    bool pair = (pv >= hv);
    int s = (((neg>>bi)&1)<<1) | ((neg>>bj)&1);
    int pidx = 4*(7*bi - ((bi*(bi-1))>>1) + (bj-bi-1)) + s;
    int hidx = 112 + (hb>>1);
    double sI = ((neg>>bi)&1)? scale : -scale;
    double sJ = ((neg>>bj)&1)? scale : -scale;
    #pragma unroll
    for (int k=0;k<8;k++){
        double cp = ((k==bi)? sI:0.0) + ((k==bj)? sJ:0.0);
        double ch = ((hb>>k)&1)? 0.5*scale : -0.5*scale;
        residual[k] += (pair? cp : ch);
    }
    return pair? pidx : hidx;
}

// ============ helpers for MFMA phase B =======================================
__device__ __forceinline__ unsigned short f2bf(float x){
    union{float f; u32 u;} c; c.f = x;
    u32 u = c.u + 0x7fffu + ((c.u>>16)&1u);
    return (unsigned short)(u>>16);
}
__device__ __forceinline__ u32 pk2(float a, float b){
    union { __hip_bfloat162 h; u32 u; } cv;
    cv.h = __float22bfloat162_rn(make_float2(a,b));
    return cv.u;
}

#define BT_PITCH 264
#define E_PITCH  260
#define SCR_PITCH 68

#define EP4(i,jn,J,W) { \
    float P=(qf[i]+qf[jn])*IS2, M=(qf[i]-qf[jn])*IS2; \
    float e0=__expf(fmaf(-LG2,bcxL[(J)+0],P)); \
    float e1=__expf(fmaf(-LG2,bcxL[(J)+1],M)); \
    float e2=__expf(fmaf(-LG2,bcxL[(J)+2],-M)); \
    float e3=__expf(fmaf(-LG2,bcxL[(J)+3],-P)); \
    den += ((e0+e1)+(e2+e3)); \
    ESH[((W)+0)*E_PITCH + tid]=pk2(e0,e1); \
    ESH[((W)+1)*E_PITCH + tid]=pk2(e2,e3); }

#define LOV(Lx) (s01[(Lx)&3]+s23[(Lx)>>2])
#define EH8(h,J,W,L0,L1,L2,L3,L4,L5,L6,L7) { \
    float hv=s45[(h)&3]+s67[(h)>>2]; \
    float e0=__expf(fmaf(-LG2,bcxL[(J)+0],(LOV(L0)+hv)*HS2)); \
    float e1=__expf(fmaf(-LG2,bcxL[(J)+1],(LOV(L1)+hv)*HS2)); \
    float e2=__expf(fmaf(-LG2,bcxL[(J)+2],(LOV(L2)+hv)*HS2)); \
    float e3=__expf(fmaf(-LG2,bcxL[(J)+3],(LOV(L3)+hv)*HS2)); \
    float e4=__expf(fmaf(-LG2,bcxL[(J)+4],(LOV(L4)+hv)*HS2)); \
    float e5=__expf(fmaf(-LG2,bcxL[(J)+5],(LOV(L5)+hv)*HS2)); \
    float e6=__expf(fmaf(-LG2,bcxL[(J)+6],(LOV(L6)+hv)*HS2)); \
    float e7=__expf(fmaf(-LG2,bcxL[(J)+7],(LOV(L7)+hv)*HS2)); \
    den += (((e0+e1)+(e2+e3))+((e4+e5)+(e6+e7))); \
    ESH[((W)+0)*E_PITCH + tid]=pk2(e0,e1); \
    ESH[((W)+1)*E_PITCH + tid]=pk2(e2,e3); \
    ESH[((W)+2)*E_PITCH + tid]=pk2(e4,e5); \
    ESH[((W)+3)*E_PITCH + tid]=pk2(e6,e7); }

#define EFLUSH(c) { \
    union { u32 u[4]; bf16x8 v; } Af; \
    const unsigned short* bp = BtT + pp*BT_PITCH + qq*8 + (c)*32; \
    bf16x8 b0 = *(const bf16x8*)(const void*)(bp); \
    bf16x8 b1 = *(const bf16x8*)(const void*)(bp + 16*BT_PITCH); \
    bf16x8 b2 = *(const bf16x8*)(const void*)(bp + 32*BT_PITCH); \
    bf16x8 b3 = *(const bf16x8*)(const void*)(bp + 48*BT_PITCH); \
    _Pragma("unroll") for (int s4=0;s4<4;s4++){ \
        const u32* ep = ESH + (4*qq)*E_PITCH + wbase + 16*s4 + pp; \
        Af.u[0]=ep[0]; Af.u[1]=ep[E_PITCH]; Af.u[2]=ep[2*E_PITCH]; Af.u[3]=ep[3*E_PITCH]; \
        acc[s4][0]=__builtin_amdgcn_mfma_f32_16x16x32_bf16(Af.v,b0,acc[s4][0],0,0,0); \
        acc[s4][1]=__builtin_amdgcn_mfma_f32_16x16x32_bf16(Af.v,b1,acc[s4][1],0,0,0); \
        acc[s4][2]=__builtin_amdgcn_mfma_f32_16x16x32_bf16(Af.v,b2,acc[s4][2],0,0,0); \
        acc[s4][3]=__builtin_amdgcn_mfma_f32_16x16x32_bf16(Af.v,b3,acc[s4][3],0,0,0); \
    } }

// ============ K_A: fp32 MLP + analytic scan; writes q + packed idxs into out ==
__global__ __launch_bounds__(TPB) void e8_phaseA(
    const float* __restrict__ g_obs,
    const float* __restrict__ pw1, const float* __restrict__ pb1,
    const float* __restrict__ pw2, const float* __restrict__ pb2,
    const float* __restrict__ glogdecay,
    u32* __restrict__ cnt, u32* __restrict__ list,
    unsigned char* __restrict__ flags, int useCompact,
    float* __restrict__ out, int B)
{
    __shared__ float obsF[TPB*17];     // 17.4 KB coalesced obs staging
    const int tid = threadIdx.x;
    const int row = blockIdx.x*TPB + tid;
    const bool active = row < B;
    const int lane = tid & 63;

    {
        const size_t base = (size_t)blockIdx.x*TPB*14;
        const size_t lim  = (size_t)B*14;
        for (int t = tid; t < TPB*14; t += TPB){
            size_t g = base + (size_t)t;
            float v = (g < lim) ? g_obs[g] : 0.f;
            int r = t/14, c = t - r*14;
            obsF[r*17 + c] = v;
        }
    }
    __syncthreads();

    float qf[8];
    int idxs[8] = {0,0,0,0,0,0,0,0};
    bool flag = false;
    {
        float ob[14];
        #pragma unroll
        for (int j=0;j<14;j++) ob[j]=obsF[tid*17+j];
        float qa[8];
        #pragma unroll
        for (int m=0;m<8;m++) qa[m]=pb2[m];
        #pragma unroll 1
        for (int k=0;k<32;k++){
            float a = pb1[k];
            #pragma unroll
            for (int j=0;j<14;j++) a = fmaf(pw1[k*14+j], ob[j], a);
            float h = 0.5f*a*(1.f+erff(a*0.70710678f));
            #pragma unroll
            for (int m=0;m<8;m++) qa[m] = fmaf(pw2[m*32+k], h, qa[m]);
        }
        float n2=0.f;
        #pragma unroll
        for (int m=0;m<8;m++) n2 = fmaf(qa[m],qa[m],n2);
        float nr = fmaxf(sqrtf(n2), 1e-12f);
        float sc = 1.41421356237309505f/nr;
        float residual[8];
        #pragma unroll
        for (int m=0;m<8;m++){ qf[m]=qa[m]*sc; residual[m]=qf[m]; }

        float decay = expf(glogdecay[0]);
        float dpow = 1.f;
        #pragma unroll
        for (int lvl=0; lvl<8; ++lvl){
            float rs = 0.5f*dpow;
            float x[8];
            #pragma unroll
            for (int k=0;k<8;k++) x[k]=residual[k]*rs;
            idxs[lvl] = scan_fast(x, 2.f/dpow, residual, (lvl<3), flag);
            dpow *= decay;
        }
    }
    flag = flag && active;

    if (useCompact){
        u64 mask = __ballot(flag);
        if (mask){
            int leader = __builtin_ctzll(mask);
            u32 base = 0;
            if (lane == leader) base = atomicAdd(cnt, (u32)__builtin_popcountll(mask));
            base = __shfl(base, leader, 64);
            if (flag){
                u32 pos = (u32)__builtin_popcountll(mask & ((1ull<<lane)-1ull));
                list[base+pos] = (u32)row;
            }
        }
    } else if (active){
        flags[row] = flag ? 1 : 0;
    }

    if (active){
        float* orow = out + (size_t)row*56;
        *(float4*)(orow+0) = make_float4(qf[0],qf[1],qf[2],qf[3]);
        *(float4*)(orow+4) = make_float4(qf[4],qf[5],qf[6],qf[7]);
        u32 iw0 = (u32)idxs[1] | ((u32)idxs[2]<<8) | ((u32)idxs[3]<<16) | ((u32)idxs[4]<<24);
        u32 iw1 = (u32)idxs[5] | ((u32)idxs[6]<<8) | ((u32)idxs[7]<<16);
        union{ u32 u[2]; float2 f; } iv; iv.u[0]=iw0; iv.u[1]=iw1;
        *(float2*)(orow+8) = iv.f;
    }
}

// ============ K_R: rescue — f64 MLP+scan for near-tie rows, thread per row ====
// Runs BETWEEN phaseA and phaseB: overwrites the flagged rows' q/idxs slots in
// out with f64-derived values, so phaseB (MFMA path) processes them with the
// stable indices. Eliminates the separate fp32 rescue-phaseB kernel entirely:
// rescue was about argmin INDEX stability (EPS_GAP ties), and the softmax
// numerics go through the same bf16 path that passes tolerance for all other
// 262k rows.
__global__ __launch_bounds__(RTPB) void e8_rescueA(
    const float* __restrict__ g_obs,
    const float* __restrict__ pw1, const float* __restrict__ pb1,
    const float* __restrict__ pw2, const float* __restrict__ pb2,
    const float* __restrict__ glogdecay,
    const u32* __restrict__ cnt, const u32* __restrict__ list,
    const unsigned char* __restrict__ flags, int useCompact,
    float* __restrict__ out, int B)
{
    const int tid = threadIdx.x;
    int row = -1;
    if (useCompact){
        u32 c = *cnt;
        if ((u32)(blockIdx.x*RTPB) >= c) return;
        u32 gid = blockIdx.x*RTPB + tid;
        if (gid >= c) return;
        row = (int)list[gid];
    } else {
        row = blockIdx.x*RTPB + tid;
        if (row >= B || !flags[row]) return;
    }

    double ob[14];
    #pragma unroll
    for (int j=0;j<14;j++) ob[j] = (double)g_obs[(size_t)row*14+j];
    double qa[8];
    #pragma unroll
    for (int m=0;m<8;m++) qa[m] = (double)pb2[m];
    #pragma unroll 1
    for (int k=0;k<32;k++){
        double a = (double)pb1[k];
        #pragma unroll
        for (int j=0;j<14;j++) a += (double)pw1[k*14+j]*ob[j];
        double hk = 0.5*a*(1.0 + erf(a*0.70710678118654752440));
        #pragma unroll
        for (int m=0;m<8;m++) qa[m] += (double)pw2[m*32+k]*hk;
    }
    double n2 = 0.0;
    #pragma unroll
    for (int m=0;m<8;m++) n2 += qa[m]*qa[m];
    double nr = sqrt(n2); if (nr < 1e-12) nr = 1e-12;
    double q[8], residual[8];
    #pragma unroll
    for (int m=0;m<8;m++){ q[m] = qa[m]/nr*1.4142135623730951; residual[m]=q[m]; }

    double decay_d = exp((double)glogdecay[0]);
    double dpow = 1.0;
    int idxs[8] = {0,0,0,0,0,0,0,0};
    #pragma unroll
    for (int lvl=0; lvl<8; ++lvl){
        double rs = 0.5*dpow;
        double x[8];
        #pragma unroll
        for (int k=0;k<8;k++) x[k]=residual[k]*rs;
        idxs[lvl] = scan_fast_f64(x, 2.0/dpow, residual);
        dpow *= decay_d;
    }

    float* orow = out + (size_t)row*56;
    *(float4*)(orow+0) = make_float4((float)q[0],(float)q[1],(float)q[2],(float)q[3]);
    *(float4*)(orow+4) = make_float4((float)q[4],(float)q[5],(float)q[6],(float)q[7]);
    u32 iw0 = (u32)idxs[1] | ((u32)idxs[2]<<8) | ((u32)idxs[3]<<16) | ((u32)idxs[4]<<24);
    u32 iw1 = (u32)idxs[5] | ((u32)idxs[6]<<8) | ((u32)idxs[7]<<16);
    union{ u32 u[2]; float2 f; } iv; iv.u[0]=iw0; iv.u[1]=iw1;
    *(float2*)(orow+8) = iv.f;
}

// ============ K_B: MFMA softmax-GEMM + hard gathers (R9 config, converged) ====
__global__ __launch_bounds__(TPB) void e8_phaseB(
    const float* __restrict__ lemb, const float* __restrict__ bcp,
    const float* __restrict__ rcpar, const float* __restrict__ bcx,
    const float* __restrict__ glogdecay,
    float* __restrict__ out, int B)
{
    const float IS2 = 0.70710678118654752f;
    const float HS2 = 0.35355339059327376f;
    const float LG2 = 0.69314718055994531f;

    __shared__ __align__(16) unsigned short BtT[64*BT_PITCH]; // 33792 B bf16 L^T
    __shared__ __align__(16) char UN[17408];                  // E / scratch union
    __shared__ float bcxL[240];
    u32*   ESH  = (u32*)UN;
    float* scrF = (float*)UN;

    const int tid  = threadIdx.x;
    const int row  = blockIdx.x*TPB + tid;
    const bool active = row < B;
    const int lane = tid & 63;
    const int qq = lane >> 4, pp = lane & 15;
    const int wbase = tid & 192;       // wave index * 64

    for (int t = tid; t < 2048; t += TPB)
        BtT[(56 + (t>>8))*BT_PITCH + (t&255)] = 0;
    for (int t = tid; t < 1024; t += TPB)
        BtT[(t>>4)*BT_PITCH + 240 + (t&15)] = 0;
    for (int t = tid; t < 12480; t += TPB){
        int k = t/52, c = t - k*52;
        BtT[c*BT_PITCH + k] = f2bf(lemb[t]);
    }
    for (int t = tid; t < 960; t += TPB){
        int k = t>>2, c = 52 + (t&3);
        BtT[c*BT_PITCH + k] = f2bf(bcp[t]);
    }
    for (int t = tid; t < 240; t += TPB) bcxL[t] = bcx[t];

    float qf[8];
    u32 iw0=0, iw1=0;
    if (active){
        const float* orow = out + (size_t)row*56;
        float4 q0 = *(const float4*)(orow+0);
        float4 q1 = *(const float4*)(orow+4);
        qf[0]=q0.x; qf[1]=q0.y; qf[2]=q0.z; qf[3]=q0.w;
        qf[4]=q1.x; qf[5]=q1.y; qf[6]=q1.z; qf[7]=q1.w;
        union{ float2 f; u32 u[2]; } iv;
        iv.f = *(const float2*)(orow+8);
        iw0 = iv.u[0]; iw1 = iv.u[1];
    } else {
        #pragma unroll
        for (int m=0;m<8;m++) qf[m]=0.f;
    }
    float decay = expf(glogdecay[0]);
    __syncthreads();

    float s01[4], s23[4], s45[4], s67[4];
    {
        float a01p=qf[0]+qf[1], a01m=qf[0]-qf[1];
        float a23p=qf[2]+qf[3], a23m=qf[2]-qf[3];
        float a45p=qf[4]+qf[5], a45m=qf[4]-qf[5];
        float a67p=qf[6]+qf[7], a67m=qf[6]-qf[7];
        s01[0]=a01p; s01[1]=-a01m; s01[2]=a01m; s01[3]=-a01p;
        s23[0]=a23p; s23[1]=-a23m; s23[2]=a23m; s23[3]=-a23p;
        s45[0]=a45p; s45[1]=-a45m; s45[2]=a45m; s45[3]=-a45p;
        s67[0]=a67p; s67[1]=-a67m; s67[2]=a67m; s67[3]=-a67p;
    }

    f32x4 acc[4][4];
    #pragma unroll
    for (int s=0;s<4;s++)
        #pragma unroll
        for (int n=0;n<4;n++)
            acc[s][n] = f32x4{0.f,0.f,0.f,0.f};
    float den = 0.f;

    EP4(0,1,  0, 0) EP4(0,2,  4, 2) EP4(0,3,  8, 4) EP4(0,4, 12, 6)
    EP4(0,5, 16, 8) EP4(0,6, 20,10) EP4(0,7, 24,12) EP4(1,2, 28,14)
    EFLUSH(0)
    EP4(1,3, 32, 0) EP4(1,4, 36, 2) EP4(1,5, 40, 4) EP4(1,6, 44, 6)
    EP4(1,7, 48, 8) EP4(2,3, 52,10) EP4(2,4, 56,12) EP4(2,5, 60,14)
    EFLUSH(1)
    EP4(2,6, 64, 0) EP4(2,7, 68, 2) EP4(3,4, 72, 4) EP4(3,5, 76, 6)
    EP4(3,6, 80, 8) EP4(3,7, 84,10) EP4(4,5, 88,12) EP4(4,6, 92,14)
    EFLUSH(2)
    EP4(4,7, 96, 0) EP4(5,6,100, 2) EP4(5,7,104, 4) EP4(6,7,108, 6)
    EH8(0,112, 8, 0,3,5,6,9,10,12,15)
    EH8(1,120,12, 1,2,4,7,8,11,13,14)
    EFLUSH(3)
    EH8(2,128, 0, 1,2,4,7,8,11,13,14)
    EH8(3,136, 4, 0,3,5,6,9,10,12,15)
    EH8(4,144, 8, 1,2,4,7,8,11,13,14)
    EH8(5,152,12, 0,3,5,6,9,10,12,15)
    EFLUSH(4)
    EH8(6,160, 0, 0,3,5,6,9,10,12,15)
    EH8(7,168, 4, 1,2,4,7,8,11,13,14)
    EH8(8,176, 8, 1,2,4,7,8,11,13,14)
    EH8(9,184,12, 0,3,5,6,9,10,12,15)
    EFLUSH(5)
    EH8(10,192, 0, 0,3,5,6,9,10,12,15)
    EH8(11,200, 4, 1,2,4,7,8,11,13,14)
    EH8(12,208, 8, 0,3,5,6,9,10,12,15)
    EH8(13,216,12, 1,2,4,7,8,11,13,14)
    EFLUSH(6)
    EH8(14,224, 0, 1,2,4,7,8,11,13,14)
    EH8(15,232, 4, 0,3,5,6,9,10,12,15)
    #pragma unroll
    for (int w2=8; w2<16; w2++) ESH[w2*E_PITCH + tid]=0u;
    EFLUSH(7)

    __syncthreads();

    float emb[56];
    float* scr = scrF + (tid>>6)*(16*SCR_PITCH);
    #pragma unroll
    for (int s=0;s<4;s++){
        #pragma unroll
        for (int n=0;n<4;n++){
            #pragma unroll
            for (int r=0;r<4;r++)
                scr[(4*qq+r)*SCR_PITCH + 16*n + pp] = acc[s][n][r];
        }
        if ((lane>>4) == s){
            const float4* rp = (const float4*)(scr + pp*SCR_PITCH);
            #pragma unroll
            for (int t=0;t<14;t++){
                float4 v = rp[t];
                emb[4*t]=v.x; emb[4*t+1]=v.y; emb[4*t+2]=v.z; emb[4*t+3]=v.w;
            }
        }
    }

    if (active){
        float rden = 1.f/den;
        #pragma unroll
        for (int k=0;k<56;k++) emb[k] *= rden;

        int i1 = iw0 & 255, i2 = (iw0>>8)&255, i3 = (iw0>>16)&255, i4 = (iw0>>24)&255;
        int i5 = iw1 & 255, i6 = (iw1>>8)&255, i7 = (iw1>>16)&255;

        float dp = decay;
        #define DO_G2(LVL, IV) { \
            float ild = 1.0f/dp; \
            const float4* ep4 = (const float4*)(lemb + ((size_t)(LVL)*240 + (size_t)(IV))*52); \
            _Pragma("unroll") for (int t4=0;t4<13;t4++){ float4 v=ep4[t4]; \
                emb[4*t4+0]=fmaf(ild,v.x,emb[4*t4+0]); emb[4*t4+1]=fmaf(ild,v.y,emb[4*t4+1]); \
                emb[4*t4+2]=fmaf(ild,v.z,emb[4*t4+2]); emb[4*t4+3]=fmaf(ild,v.w,emb[4*t4+3]); } \
            float4 cv = *(const float4*)(rcpar + ((size_t)((LVL)-1)*240 + (size_t)(IV))*4); \
            emb[52]=fmaf(ild,cv.x,emb[52]); emb[53]=fmaf(ild,cv.y,emb[53]); \
            emb[54]=fmaf(ild,cv.z,emb[54]); emb[55]=fmaf(ild,cv.w,emb[55]); \
            dp *= decay; }
        DO_G2(1,i1) DO_G2(2,i2) DO_G2(3,i3) DO_G2(4,i4)
        DO_G2(5,i5) DO_G2(6,i6) DO_G2(7,i7)
        #undef DO_G2

        float4* o4 = (float4*)(out + (size_t)row*56);
        #pragma unroll
        for (int t=0;t<14;t++)
            o4[t] = make_float4(emb[4*t], emb[4*t+1], emb[4*t+2], emb[4*t+3]);
    }
}

// ============ K3: gated refinement MLP (standalone, proven R6 version) =======
__global__ __launch_bounds__(TPB) void e8_refine(
    const float* __restrict__ rw1, const float* __restrict__ rb1,
    const float* __restrict__ rw2, const float* __restrict__ rb2,
    const float* __restrict__ rgate,
    float* __restrict__ out, int B)
{
    __shared__ float W1[2704];
    __shared__ float W2T[2704];
    __shared__ float Bv[104];
    const int tid = threadIdx.x;
    for (int t = tid; t < 2704; t += TPB) W1[t] = rw1[t];
    for (int t = tid; t < 2704; t += TPB){
        int m = t/52, k = t - m*52;
        W2T[k*52 + m] = rw2[t];
    }
    for (int t = tid; t < 104; t += TPB) Bv[t] = (t < 52) ? rb1[t] : rb2[t-52];
    __syncthreads();

    const int row = blockIdx.x*TPB + tid;
    if (row >= B) return;
    float* orow = out + (size_t)row*56;
    float emb[52];
    {
        const float4* o4 = (const float4*)orow;
        #pragma unroll
        for (int t=0;t<13;t++){
            float4 v = o4[t];
            emb[4*t]=v.x; emb[4*t+1]=v.y; emb[4*t+2]=v.z; emb[4*t+3]=v.w;
        }
    }
    float sg = 1.f/(1.f+__expf(-rgate[0]));
    float acc[52];
    #pragma unroll
    for (int m=0;m<52;m++) acc[m]=0.f;
    #pragma unroll 1
    for (int k=0;k<52;k++){
        const float4* w1 = (const float4*)(W1 + k*52);
        float a0=0.f,a1=0.f,a2=0.f,a3=0.f;
        #pragma unroll
        for (int t=0;t<13;t++){
            float4 w = w1[t];
            a0=fmaf(w.x,emb[4*t+0],a0); a1=fmaf(w.y,emb[4*t+1],a1);
            a2=fmaf(w.z,emb[4*t+2],a2); a3=fmaf(w.w,emb[4*t+3],a3);
        }
        float a = ((a0+a1)+(a2+a3)) + Bv[k];
        float gk = sg*0.5f*a*(1.f+erff(a*0.70710678f));
        const float4* w2 = (const float4*)(W2T + k*52);
        #pragma unroll
        for (int t=0;t<13;t++){
            float4 w = w2[t];
            acc[4*t+0]=fmaf(gk,w.x,acc[4*t+0]); acc[4*t+1]=fmaf(gk,w.y,acc[4*t+1]);
            acc[4*t+2]=fmaf(gk,w.z,acc[4*t+2]); acc[4*t+3]=fmaf(gk,w.w,acc[4*t+3]);
        }
    }
    float4* o4 = (float4*)orow;
    #pragma unroll
    for (int t=0;t<13;t++){
        float4 v;
        v.x = emb[4*t+0] + fmaf(sg, Bv[52+4*t+0], acc[4*t+0]);
        v.y = emb[4*t+1] + fmaf(sg, Bv[52+4*t+1], acc[4*t+1]);
        v.z = emb[4*t+2] + fmaf(sg, Bv[52+4*t+2], acc[4*t+2]);
        v.w = emb[4*t+3] + fmaf(sg, Bv[52+4*t+3], acc[4*t+3]);
        o4[t] = v;
    }
}

extern "C" void kernel_launch(void* const* d_in, const int* in_sizes, int n_in,
                              void* d_out, int out_size, void* d_ws, size_t ws_size,
                              hipStream_t stream)
{
    const float* obs  = (const float*)d_in[0];
    const float* pw1  = (const float*)d_in[1];
    const float* pb1  = (const float*)d_in[2];
    const float* pw2  = (const float*)d_in[3];
    const float* pb2  = (const float*)d_in[4];
    const float* lemb = (const float*)d_in[5];
    const float* bcp  = (const float*)d_in[6];
    const float* rcp  = (const float*)d_in[7];
    const float* bcx  = (const float*)d_in[8];
    const float* ld   = (const float*)d_in[9];
    const float* rw1  = (const float*)d_in[10];
    const float* rb1  = (const float*)d_in[11];
    const float* rw2  = (const float*)d_in[12];
    const float* rb2  = (const float*)d_in[13];
    const float* rg   = (const float*)d_in[14];

    int B = in_sizes[0] / 14;
    int grid  = (B + TPB - 1) / TPB;
    int rgridA = (B + RTPB - 1) / RTPB;

    bool compact = ws_size >= (size_t)256 + (size_t)B*4;
    u32* cnt  = (u32*)d_ws;
    u32* list = (u32*)d_ws + 64;
    unsigned char* flags = (unsigned char*)d_ws + 256;

    hipMemsetAsync(d_ws, 0, 8, stream);

    e8_phaseA<<<grid, TPB, 0, stream>>>(obs, pw1, pb1, pw2, pb2, ld,
                                        cnt, list, flags, compact?1:0, (float*)d_out, B);
    e8_rescueA<<<rgridA, RTPB, 0, stream>>>(obs, pw1, pb1, pw2, pb2, ld,
                                            cnt, list, flags, compact?1:0, (float*)d_out, B);
    e8_phaseB<<<grid, TPB, 0, stream>>>(lemb, bcp, rcp, bcx, ld, (float*)d_out, B);
    e8_refine<<<grid, TPB, 0, stream>>>(rw1, rb1, rw2, rb2, rg, (float*)d_out, B);
}